// Round 6
// baseline (66.133 us; speedup 1.0000x reference)
//
#include <hip/hip_runtime.h>

// Problem dims (fixed by reference setup_inputs)
constexpr int B = 4, P = 8, H = 32, W = 32, D = 32, C = 16;

using f32x4 = __attribute__((ext_vector_type(4))) float;
using f16x8 = __attribute__((ext_vector_type(8))) _Float16;

// ---------------------------------------------------------------------------
// Pass 1: fmap fp32 -> f16 into d_ws. Halves the bytes the scattered-gather
// pass must pull through the TA/L1 pipe (the measured bottleneck:
// ~32 cyc per scattered 64-lane gather instr, invariant across layouts).
// ---------------------------------------------------------------------------
__global__ __launch_bounds__(256) void cvt_kernel(const float* __restrict__ in,
                                                  _Float16* __restrict__ o) {
    const int t = blockIdx.x * 256 + threadIdx.x;        // 8 floats per thread
    const f32x4* p = (const f32x4*)in + (size_t)t * 2;
    const f32x4 a = p[0], b = p[1];
    f16x8 h;
    h[0] = (_Float16)a[0]; h[1] = (_Float16)a[1];
    h[2] = (_Float16)a[2]; h[3] = (_Float16)a[3];
    h[4] = (_Float16)b[0]; h[5] = (_Float16)b[1];
    h[6] = (_Float16)b[2]; h[7] = (_Float16)b[3];
    *((f16x8*)o + t) = h;    // normal store: pass 2 wants this L2-resident
}

// ---------------------------------------------------------------------------
// Pass 2: one thread per voxel. 16 f16x8 gathers (8 corners x 16ch), weights
// in fp32 (one f16 quantization each), two 4-deep f16 FMA chains combined in
// fp32 (bounds accumulation error), fp32 NT stores.
// ---------------------------------------------------------------------------
__global__ __launch_bounds__(256) void gather_kernel(
    const _Float16* __restrict__ fmap16,   // [B,P,H,W,D,C] f16
    const float* __restrict__ theta,       // [B,P,3,4]
    float* __restrict__ out)               // [B,P,H,W,D,C] f32
{
    // 4096 blocks = 32 bp-slices x 128. XCD swizzle (bijective, nwg%8==0):
    // each XCD walks consecutive blocks -> bp slice (1 MB f16) is L2-local.
    const int orig = blockIdx.x;
    const int virt = (orig & 7) * 512 + (orig >> 3);
    const int vox  = virt * 256 + threadIdx.x;
    const int k = vox & (D - 1);
    const int j = (vox >> 5) & (W - 1);
    const int i = (vox >> 10) & (H - 1);
    const int bp = vox >> 15;                       // block-uniform

    const float4* th4 = (const float4*)(theta + bp * 12);
    const float4 t0 = th4[0];   // -> y_s
    const float4 t1 = th4[1];   // -> x_s
    const float4 t2 = th4[2];   // -> z_s

    const float fi = (float)i, fj = (float)j, fk = (float)k;
    const float y = fmaf(t0.x, fi, fmaf(t0.y, fj, fmaf(t0.z, fk, t0.w))) + 2.0f;
    const float x = fmaf(t1.x, fi, fmaf(t1.y, fj, fmaf(t1.z, fk, t1.w))) + 2.0f;
    const float z = fmaf(t2.x, fi, fmaf(t2.y, fj, fmaf(t2.z, fk, t2.w))) + 2.0f;

    // ref: ?0 = clip(floor(?), 0, 34); ?d = ? - ?0 (NOT re-clamped)
    const float fy0 = fminf(fmaxf(floorf(y), 0.0f), 34.0f);
    const float fx0 = fminf(fmaxf(floorf(x), 0.0f), 34.0f);
    const float fz0 = fminf(fmaxf(floorf(z), 0.0f), 34.0f);
    const float yd = y - fy0, xd = x - fx0, zd = z - fz0;
    const int ty0 = (int)fy0 - 2, tx0 = (int)fx0 - 2, tz0 = (int)fz0 - 2;

    // Branchless pad: OOB tap -> weight 0 + clamped-safe address. All taps
    // with nonzero weight have wy,wx,wz in [0,1] (clipped coords always OOB).
    float wy[2], wx[2], wz[2];
    int   iy[2], ix[2], iz[2];
    wy[0] = ((unsigned)ty0       < (unsigned)H) ? (1.0f - yd) : 0.0f;
    wy[1] = ((unsigned)(ty0 + 1) < (unsigned)H) ? yd          : 0.0f;
    wx[0] = ((unsigned)tx0       < (unsigned)W) ? (1.0f - xd) : 0.0f;
    wx[1] = ((unsigned)(tx0 + 1) < (unsigned)W) ? xd          : 0.0f;
    wz[0] = ((unsigned)tz0       < (unsigned)D) ? (1.0f - zd) : 0.0f;
    wz[1] = ((unsigned)(tz0 + 1) < (unsigned)D) ? zd          : 0.0f;
    iy[0] = min(max(ty0, 0), H - 1);  iy[1] = min(max(ty0 + 1, 0), H - 1);
    ix[0] = min(max(tx0, 0), W - 1);  ix[1] = min(max(tx0 + 1, 0), W - 1);
    iz[0] = min(max(tz0, 0), D - 1);  iz[1] = min(max(tz0 + 1, 0), D - 1);

    int   off[8];
    float w[8];
    #pragma unroll
    for (int a = 0; a < 2; ++a)
        #pragma unroll
        for (int b2 = 0; b2 < 2; ++b2)
            #pragma unroll
            for (int c2 = 0; c2 < 2; ++c2) {
                const int cn = a * 4 + b2 * 2 + c2;
                off[cn] = ((iy[a] * W + ix[b2]) * D + iz[c2]) * C;
                w[cn]   = wy[a] * wx[b2] * wz[c2];
            }

    const _Float16* base = fmap16 + (size_t)bp * (H * W * D * C);

    // Issue all 16 loads first (max MLP), then blend.
    f16x8 v0[8], v1[8];
    #pragma unroll
    for (int cn = 0; cn < 8; ++cn) {
        v0[cn] = *(const f16x8*)(base + off[cn]);
        v1[cn] = *(const f16x8*)(base + off[cn] + 8);
    }

    // Two 4-deep f16 chains per half, combined in f32 (limits f16 round-off).
    f16x8 aA0 = 0, aA1 = 0, aB0 = 0, aB1 = 0;
    #pragma unroll
    for (int cn = 0; cn < 4; ++cn) {
        const _Float16 hw = (_Float16)w[cn];
        aA0 += hw * v0[cn];
        aA1 += hw * v1[cn];
    }
    #pragma unroll
    for (int cn = 4; cn < 8; ++cn) {
        const _Float16 hw = (_Float16)w[cn];
        aB0 += hw * v0[cn];
        aB1 += hw * v1[cn];
    }

    float r[16];
    #pragma unroll
    for (int c = 0; c < 8; ++c) {
        r[c]     = (float)aA0[c] + (float)aB0[c];
        r[c + 8] = (float)aA1[c] + (float)aB1[c];
    }

    float* op = out + (size_t)vox * C;
    __builtin_nontemporal_store(*(f32x4*)&r[0],  (f32x4*)op);
    __builtin_nontemporal_store(*(f32x4*)&r[4],  (f32x4*)(op + 4));
    __builtin_nontemporal_store(*(f32x4*)&r[8],  (f32x4*)(op + 8));
    __builtin_nontemporal_store(*(f32x4*)&r[12], (f32x4*)(op + 12));
}

// ---------------------------------------------------------------------------
// Fallback (ws too small): round-2 fp32 kernel, known-good at 29.1 us.
// ---------------------------------------------------------------------------
__global__ __launch_bounds__(256) void fallback_kernel(
    const float* __restrict__ fmap, const float* __restrict__ theta,
    float* __restrict__ out)
{
    const int bp  = blockIdx.x >> 9;
    const int tid = threadIdx.x;
    const int c4  = tid & 3;
    const int vox = blockIdx.x * 64 + (tid >> 2);
    const int k   =  vox        & (D - 1);
    const int j   = (vox >> 5)  & (W - 1);
    const int i   = (vox >> 10) & (H - 1);

    const float4* th4 = (const float4*)(theta + bp * 12);
    const float4 t0 = th4[0], t1 = th4[1], t2 = th4[2];

    const float fi = (float)i, fj = (float)j, fk = (float)k;
    const float y = fmaf(t0.x, fi, fmaf(t0.y, fj, fmaf(t0.z, fk, t0.w))) + 2.0f;
    const float x = fmaf(t1.x, fi, fmaf(t1.y, fj, fmaf(t1.z, fk, t1.w))) + 2.0f;
    const float z = fmaf(t2.x, fi, fmaf(t2.y, fj, fmaf(t2.z, fk, t2.w))) + 2.0f;

    const float fy0 = fminf(fmaxf(floorf(y), 0.0f), 34.0f);
    const float fx0 = fminf(fmaxf(floorf(x), 0.0f), 34.0f);
    const float fz0 = fminf(fmaxf(floorf(z), 0.0f), 34.0f);
    const float yd = y - fy0, xd = x - fx0, zd = z - fz0;
    const int ty0 = (int)fy0 - 2, tx0 = (int)fx0 - 2, tz0 = (int)fz0 - 2;

    float wy[2], wx[2], wz[2];
    int   iy[2], ix[2], iz[2];
    wy[0] = ((unsigned)ty0       < (unsigned)H) ? (1.0f - yd) : 0.0f;
    wy[1] = ((unsigned)(ty0 + 1) < (unsigned)H) ? yd          : 0.0f;
    wx[0] = ((unsigned)tx0       < (unsigned)W) ? (1.0f - xd) : 0.0f;
    wx[1] = ((unsigned)(tx0 + 1) < (unsigned)W) ? xd          : 0.0f;
    wz[0] = ((unsigned)tz0       < (unsigned)D) ? (1.0f - zd) : 0.0f;
    wz[1] = ((unsigned)(tz0 + 1) < (unsigned)D) ? zd          : 0.0f;
    iy[0] = min(max(ty0, 0), H - 1);  iy[1] = min(max(ty0 + 1, 0), H - 1);
    ix[0] = min(max(tx0, 0), W - 1);  ix[1] = min(max(tx0 + 1, 0), W - 1);
    iz[0] = min(max(tz0, 0), D - 1);  iz[1] = min(max(tz0 + 1, 0), D - 1);

    const float* base = fmap + bp * (H * W * D * C) + c4 * 4;
    f32x4 acc = {0.f, 0.f, 0.f, 0.f};
    #pragma unroll
    for (int a = 0; a < 2; ++a)
        #pragma unroll
        for (int b2 = 0; b2 < 2; ++b2)
            #pragma unroll
            for (int c2 = 0; c2 < 2; ++c2) {
                const float wgt = wy[a] * wx[b2] * wz[c2];
                const f32x4 v = *(const f32x4*)(
                    base + ((iy[a] * W + ix[b2]) * D + iz[c2]) * C);
                acc += wgt * v;
            }
    *(f32x4*)(out + (size_t)vox * C + c4 * 4) = acc;
}

extern "C" void kernel_launch(void* const* d_in, const int* in_sizes, int n_in,
                              void* d_out, int out_size, void* d_ws, size_t ws_size,
                              hipStream_t stream) {
    const float* fmap  = (const float*)d_in[0];
    const float* theta = (const float*)d_in[1];
    float* out = (float*)d_out;

    const size_t need = (size_t)(B * P * H * W * D * C) * sizeof(_Float16);
    if (ws_size >= need) {
        _Float16* f16buf = (_Float16*)d_ws;
        const int cvt_blocks = (B * P * H * W * D * C / 8) / 256;     // 8192
        cvt_kernel<<<cvt_blocks, 256, 0, stream>>>(fmap, f16buf);
        const int gat_blocks = (B * P * H * W * D) / 256;             // 4096
        gather_kernel<<<gat_blocks, 256, 0, stream>>>(f16buf, theta, out);
    } else {
        const int total_threads = B * P * H * W * D * 4;
        fallback_kernel<<<total_threads / 256, 256, 0, stream>>>(fmap, theta, out);
    }
}

// Round 7
// 42.076 us; speedup vs baseline: 1.5717x; 1.5717x over previous
//
#include <hip/hip_runtime.h>

// Problem dims (fixed by reference setup_inputs)
constexpr int B = 4, P = 8, H = 32, W = 32, D = 32, C = 16;

using f32x4 = __attribute__((ext_vector_type(4))) float;
using f16x8 = __attribute__((ext_vector_type(8))) _Float16;

// ---------------------------------------------------------------------------
// Pass 1: fmap fp32 -> f16 into d_ws (halves gather lane-requests, the
// measured wall: ~2 scattered 16B lane-requests/cyc/CU). NT loads keep the
// dead fp32 stream out of L2; normal stores keep the f16 buffer L2/L3-hot.
// ---------------------------------------------------------------------------
__global__ __launch_bounds__(256) void cvt_kernel(const float* __restrict__ in,
                                                  _Float16* __restrict__ o) {
    const int t = blockIdx.x * 256 + threadIdx.x;        // 8 floats per thread
    const f32x4* p = (const f32x4*)in + (size_t)t * 2;
    const f32x4 a = __builtin_nontemporal_load(p);
    const f32x4 b = __builtin_nontemporal_load(p + 1);
    f16x8 h;
    h[0] = (_Float16)a[0]; h[1] = (_Float16)a[1];
    h[2] = (_Float16)a[2]; h[3] = (_Float16)a[3];
    h[4] = (_Float16)b[0]; h[5] = (_Float16)b[1];
    h[6] = (_Float16)b[2]; h[7] = (_Float16)b[3];
    *((f16x8*)o + t) = h;
}

// ---------------------------------------------------------------------------
// Pass 2: 2 threads per voxel (each owns 8 channels). 8 f16x8 gathers per
// thread (16B/lane = max per request). f32 accumulation. Stores: lane L
// writes 32B at 32*L -> each wave's store instructions are lane-contiguous;
// PLAIN stores so L2 write-combines full lines (round-6 NT lesson).
// ---------------------------------------------------------------------------
__global__ __launch_bounds__(256, 4) void gather_kernel(
    const _Float16* __restrict__ fmap16,   // [B,P,H,W,D,C] f16
    const float* __restrict__ theta,       // [B,P,3,4]
    float* __restrict__ out)               // [B,P,H,W,D,C] f32
{
    // 8192 blocks = 32 bp-slices x 256. XCD swizzle (bijective, nwg%8==0):
    // consecutive blocks of a bp slice (1 MB f16) stay on one XCD's L2.
    const int orig = blockIdx.x;
    const int virt = (orig & 7) * 1024 + (orig >> 3);
    const int tid  = threadIdx.x;
    const int h8   = tid & 1;                     // channel half (0..7 / 8..15)
    const int vox  = virt * 128 + (tid >> 1);
    const int k = vox & (D - 1);
    const int j = (vox >> 5) & (W - 1);
    const int i = (vox >> 10) & (H - 1);
    const int bp = virt >> 8;                     // block-uniform

    const float4* th4 = (const float4*)(theta + bp * 12);
    const float4 t0 = th4[0];   // -> y_s
    const float4 t1 = th4[1];   // -> x_s
    const float4 t2 = th4[2];   // -> z_s

    const float fi = (float)i, fj = (float)j, fk = (float)k;
    const float y = fmaf(t0.x, fi, fmaf(t0.y, fj, fmaf(t0.z, fk, t0.w))) + 2.0f;
    const float x = fmaf(t1.x, fi, fmaf(t1.y, fj, fmaf(t1.z, fk, t1.w))) + 2.0f;
    const float z = fmaf(t2.x, fi, fmaf(t2.y, fj, fmaf(t2.z, fk, t2.w))) + 2.0f;

    // ref: ?0 = clip(floor(?), 0, 34); ?d = ? - ?0 (NOT re-clamped)
    const float fy0 = fminf(fmaxf(floorf(y), 0.0f), 34.0f);
    const float fx0 = fminf(fmaxf(floorf(x), 0.0f), 34.0f);
    const float fz0 = fminf(fmaxf(floorf(z), 0.0f), 34.0f);
    const float yd = y - fy0, xd = x - fx0, zd = z - fz0;
    const int ty0 = (int)fy0 - 2, tx0 = (int)fx0 - 2, tz0 = (int)fz0 - 2;

    // Branchless pad: OOB tap -> weight 0 + clamped-safe address.
    float wy[2], wx[2], wz[2];
    int   iy[2], ix[2], iz[2];
    wy[0] = ((unsigned)ty0       < (unsigned)H) ? (1.0f - yd) : 0.0f;
    wy[1] = ((unsigned)(ty0 + 1) < (unsigned)H) ? yd          : 0.0f;
    wx[0] = ((unsigned)tx0       < (unsigned)W) ? (1.0f - xd) : 0.0f;
    wx[1] = ((unsigned)(tx0 + 1) < (unsigned)W) ? xd          : 0.0f;
    wz[0] = ((unsigned)tz0       < (unsigned)D) ? (1.0f - zd) : 0.0f;
    wz[1] = ((unsigned)(tz0 + 1) < (unsigned)D) ? zd          : 0.0f;
    iy[0] = min(max(ty0, 0), H - 1);  iy[1] = min(max(ty0 + 1, 0), H - 1);
    ix[0] = min(max(tx0, 0), W - 1);  ix[1] = min(max(tx0 + 1, 0), W - 1);
    iz[0] = min(max(tz0, 0), D - 1);  iz[1] = min(max(tz0 + 1, 0), D - 1);

    int   off[8];
    float w[8];
    #pragma unroll
    for (int a = 0; a < 2; ++a)
        #pragma unroll
        for (int b2 = 0; b2 < 2; ++b2)
            #pragma unroll
            for (int c2 = 0; c2 < 2; ++c2) {
                const int cn = a * 4 + b2 * 2 + c2;
                off[cn] = ((iy[a] * W + ix[b2]) * D + iz[c2]) * C;
                w[cn]   = wy[a] * wx[b2] * wz[c2];
            }

    const _Float16* base = fmap16 + (size_t)bp * (H * W * D * C) + h8 * 8;

    // Issue all 8 loads first (MLP), then blend in f32.
    f16x8 v[8];
    #pragma unroll
    for (int cn = 0; cn < 8; ++cn)
        v[cn] = *(const f16x8*)(base + off[cn]);

    f32x4 acc0 = {0.f, 0.f, 0.f, 0.f};
    f32x4 acc1 = {0.f, 0.f, 0.f, 0.f};
    #pragma unroll
    for (int cn = 0; cn < 8; ++cn) {
        const float wc = w[cn];
        acc0[0] = fmaf(wc, (float)v[cn][0], acc0[0]);
        acc0[1] = fmaf(wc, (float)v[cn][1], acc0[1]);
        acc0[2] = fmaf(wc, (float)v[cn][2], acc0[2]);
        acc0[3] = fmaf(wc, (float)v[cn][3], acc0[3]);
        acc1[0] = fmaf(wc, (float)v[cn][4], acc1[0]);
        acc1[1] = fmaf(wc, (float)v[cn][5], acc1[1]);
        acc1[2] = fmaf(wc, (float)v[cn][6], acc1[2]);
        acc1[3] = fmaf(wc, (float)v[cn][7], acc1[3]);
    }

    // lane L stores 32B at out_base + 32*L: wave stores are lane-contiguous.
    float* op = out + (size_t)vox * C + h8 * 8;
    *(f32x4*)op       = acc0;
    *(f32x4*)(op + 4) = acc1;
}

// ---------------------------------------------------------------------------
// Fallback (ws too small): round-2/3 fp32 kernel, known-good ~29 us.
// ---------------------------------------------------------------------------
__global__ __launch_bounds__(256) void fallback_kernel(
    const float* __restrict__ fmap, const float* __restrict__ theta,
    float* __restrict__ out)
{
    const int bp  = blockIdx.x >> 9;
    const int tid = threadIdx.x;
    const int c4  = tid & 3;
    const int vox = blockIdx.x * 64 + (tid >> 2);
    const int k   =  vox        & (D - 1);
    const int j   = (vox >> 5)  & (W - 1);
    const int i   = (vox >> 10) & (H - 1);

    const float4* th4 = (const float4*)(theta + bp * 12);
    const float4 t0 = th4[0], t1 = th4[1], t2 = th4[2];

    const float fi = (float)i, fj = (float)j, fk = (float)k;
    const float y = fmaf(t0.x, fi, fmaf(t0.y, fj, fmaf(t0.z, fk, t0.w))) + 2.0f;
    const float x = fmaf(t1.x, fi, fmaf(t1.y, fj, fmaf(t1.z, fk, t1.w))) + 2.0f;
    const float z = fmaf(t2.x, fi, fmaf(t2.y, fj, fmaf(t2.z, fk, t2.w))) + 2.0f;

    const float fy0 = fminf(fmaxf(floorf(y), 0.0f), 34.0f);
    const float fx0 = fminf(fmaxf(floorf(x), 0.0f), 34.0f);
    const float fz0 = fminf(fmaxf(floorf(z), 0.0f), 34.0f);
    const float yd = y - fy0, xd = x - fx0, zd = z - fz0;
    const int ty0 = (int)fy0 - 2, tx0 = (int)fx0 - 2, tz0 = (int)fz0 - 2;

    float wy[2], wx[2], wz[2];
    int   iy[2], ix[2], iz[2];
    wy[0] = ((unsigned)ty0       < (unsigned)H) ? (1.0f - yd) : 0.0f;
    wy[1] = ((unsigned)(ty0 + 1) < (unsigned)H) ? yd          : 0.0f;
    wx[0] = ((unsigned)tx0       < (unsigned)W) ? (1.0f - xd) : 0.0f;
    wx[1] = ((unsigned)(tx0 + 1) < (unsigned)W) ? xd          : 0.0f;
    wz[0] = ((unsigned)tz0       < (unsigned)D) ? (1.0f - zd) : 0.0f;
    wz[1] = ((unsigned)(tz0 + 1) < (unsigned)D) ? zd          : 0.0f;
    iy[0] = min(max(ty0, 0), H - 1);  iy[1] = min(max(ty0 + 1, 0), H - 1);
    ix[0] = min(max(tx0, 0), W - 1);  ix[1] = min(max(tx0 + 1, 0), W - 1);
    iz[0] = min(max(tz0, 0), D - 1);  iz[1] = min(max(tz0 + 1, 0), D - 1);

    const float* base = fmap + bp * (H * W * D * C) + c4 * 4;
    f32x4 acc = {0.f, 0.f, 0.f, 0.f};
    #pragma unroll
    for (int a = 0; a < 2; ++a)
        #pragma unroll
        for (int b2 = 0; b2 < 2; ++b2)
            #pragma unroll
            for (int c2 = 0; c2 < 2; ++c2) {
                const float wgt = wy[a] * wx[b2] * wz[c2];
                const f32x4 v = *(const f32x4*)(
                    base + ((iy[a] * W + ix[b2]) * D + iz[c2]) * C);
                acc += wgt * v;
            }
    *(f32x4*)(out + (size_t)vox * C + c4 * 4) = acc;
}

extern "C" void kernel_launch(void* const* d_in, const int* in_sizes, int n_in,
                              void* d_out, int out_size, void* d_ws, size_t ws_size,
                              hipStream_t stream) {
    const float* fmap  = (const float*)d_in[0];
    const float* theta = (const float*)d_in[1];
    float* out = (float*)d_out;

    const size_t need = (size_t)(B * P * H * W * D * C) * sizeof(_Float16);
    if (ws_size >= need) {
        _Float16* f16buf = (_Float16*)d_ws;
        const int cvt_blocks = (B * P * H * W * D * C / 8) / 256;     // 8192
        cvt_kernel<<<cvt_blocks, 256, 0, stream>>>(fmap, f16buf);
        const int gat_blocks = (B * P * H * W * D * 2) / 256;         // 8192
        gather_kernel<<<gat_blocks, 256, 0, stream>>>(f16buf, theta, out);
    } else {
        const int total_threads = B * P * H * W * D * 4;
        fallback_kernel<<<total_threads / 256, 256, 0, stream>>>(fmap, theta, out);
    }
}